// Round 18
// baseline (87.240 us; speedup 1.0000x reference)
//
#include <hip/hip_runtime.h>
#include <cmath>

typedef __attribute__((ext_vector_type(4))) float f32x4;
typedef __attribute__((ext_vector_type(8))) short bf16x8;
typedef __attribute__((ext_vector_type(8))) unsigned short u16x8;

#define TSEQ 4096
#define NB 2
#define HID 2048
#define DD 64
#define NH 4
#define NROW 8192
#define SCALE 0.125f
#define NEG_HUGE -3.3e38f
#define LOG2E 1.4426950408889634f

#if __has_builtin(__builtin_amdgcn_exp2f)
#define EXP2(x) __builtin_amdgcn_exp2f(x)
#else
#define EXP2(x) exp2f(x)
#endif

__device__ __forceinline__ float sanef(float v) {
    return fminf(fmaxf(v, -3.3e38f), 3.3e38f);   // NaN->-3.3e38, +/-inf clamped
}
__device__ __forceinline__ unsigned short f2bf(float f) {  // RNE fp32->bf16
    unsigned int u = __float_as_uint(f);
    unsigned int r = u + 0x7FFF + ((u >> 16) & 1);
    return (unsigned short)(r >> 16);
}
__device__ __forceinline__ float sigm(float z) {
    return 1.0f / (1.0f + __expf(-z));
}
__device__ __forceinline__ void gload16(const unsigned short* g, unsigned short* l) {
    __builtin_amdgcn_global_load_lds(
        (const __attribute__((address_space(1))) void*)g,
        (__attribute__((address_space(3))) void*)l, 16, 0, 0);
}

// Fragment-order layouts (score reads = base + lane*8 + const, 1KB/wave):
//   Qf[(((row>>4)*4 + h)*2 + kk)*512 + (q4*16 + (row&15))*8 + el]
//   Kf[(((row>>4)*2 + kk))*512 + (q4*16 + (row&15))*8 + el]

// ============ Kernel 0: masked-region fill (launched FIRST; no deps) ============
// Pure streaming fill of strict-upper 128x128 tiles -> memset-rate writes,
// and removes fill/compute CU interference from the score kernel.
__global__ __launch_bounds__(256)
void score_fill(float* __restrict__ out)
{
    const int u = blockIdx.x, b = blockIdx.y;
    int p = (int)((sqrtf(8.f * u + 1.f) + 1.f) * 0.5f);
    while (p * (p - 1) / 2 > u) --p;
    while ((p + 1) * p / 2 <= u) ++p;
    const int q = u - p * (p - 1) / 2;
    const size_t obase = ((size_t)b * TSEQ + (size_t)q * 128) * TSEQ + (size_t)p * 128;
    const int tid = threadIdx.x;
    const int row = tid >> 1, half = tid & 1;
    float4* po = (float4*)(out + obase + (size_t)row * TSEQ + half * 64);
    const float4 nh = make_float4(NEG_HUGE, NEG_HUGE, NEG_HUGE, NEG_HUGE);
    #pragma unroll
    for (int i = 0; i < 16; ++i) po[i] = nh;
}

// ============ Kernel 1: weight concat [384][2048] bf16 ============
__global__ __launch_bounds__(256)
void cvt_w(const float* __restrict__ Wq, const float* __restrict__ Wk,
           const float* __restrict__ Ww, unsigned short* __restrict__ Wc)
{
    const int r = blockIdx.x;
    const int c0 = threadIdx.x * 8;
    const float* src = nullptr;
    if (r < 256)      src = Wq + (size_t)r * HID;
    else if (r < 320) src = Wk + (size_t)(r - 256) * HID;
    else if (r < 324) src = Ww + (size_t)(r - 320) * HID;
    u16x8 o = {0, 0, 0, 0, 0, 0, 0, 0};
    if (src) {
        const float4 a = *(const float4*)(src + c0);
        const float4 b = *(const float4*)(src + c0 + 4);
        o[0] = f2bf(a.x); o[1] = f2bf(a.y); o[2] = f2bf(a.z); o[3] = f2bf(a.w);
        o[4] = f2bf(b.x); o[5] = f2bf(b.y); o[6] = f2bf(b.z); o[7] = f2bf(b.w);
    }
    *(u16x8*)(Wc + (size_t)r * HID + c0) = o;
}

// ============ Kernel 2: fused cvt_x + projection GEMM, 64x64 tiles ============
// r9/r15 known-good main loop; epilogue writes Q/K in MFMA-fragment order.
__global__ __launch_bounds__(256)
void proj_mfma(const float* __restrict__ x,
               const unsigned short* __restrict__ Wc,
               const float* __restrict__ bw,
               unsigned short* __restrict__ Qf,
               unsigned short* __restrict__ Kf,
               float* __restrict__ Wo)
{
    __shared__ unsigned short As[64 * 64];    // 8 KB
    __shared__ unsigned short Bs[64 * 64];    // 8 KB
    const int bid = blockIdx.x;
    const int w   = (bid & 7) * 96 + (bid >> 3);     // 768 = 8*96, bijective
    const int row0 = (w / 6) * 64;
    const int col0 = (w % 6) * 64;

    const int tid  = threadIdx.x;
    const int lane = tid & 63, wid = tid >> 6;
    const int wr = wid >> 1, wc = wid & 1;           // wave tile 32x32
    const int fr = lane & 15;

    const int ar = tid >> 2, ac2 = (tid & 3) * 2, asw = ar & 7;
    const float* Axg = x + (size_t)(row0 + ar) * HID + (tid & 3) * 16;

    const int sr = tid >> 3;
    const int scs = ((tid & 7) ^ (sr & 7)) * 8;
    const unsigned short* Bg = Wc + (size_t)(col0 + sr) * HID + scs;

    f32x4 acc[2][2];
    #pragma unroll
    for (int i = 0; i < 2; ++i)
        #pragma unroll
        for (int j = 0; j < 2; ++j) acc[i][j] = (f32x4){0.f, 0.f, 0.f, 0.f};

    for (int kt = 0; kt < HID; kt += 64) {
        const float4 a0 = *(const float4*)(Axg + kt);
        const float4 a1 = *(const float4*)(Axg + kt + 4);
        const float4 a2 = *(const float4*)(Axg + kt + 8);
        const float4 a3 = *(const float4*)(Axg + kt + 12);
        __syncthreads();
        #pragma unroll
        for (int c2 = 0; c2 < 2; ++c2)
            gload16(Bg + (size_t)c2 * 32 * HID + kt, &Bs[wid * 512 + c2 * 2048]);
        u16x8 c0v, c1v;
        c0v[0] = f2bf(a0.x); c0v[1] = f2bf(a0.y); c0v[2] = f2bf(a0.z); c0v[3] = f2bf(a0.w);
        c0v[4] = f2bf(a1.x); c0v[5] = f2bf(a1.y); c0v[6] = f2bf(a1.z); c0v[7] = f2bf(a1.w);
        c1v[0] = f2bf(a2.x); c1v[1] = f2bf(a2.y); c1v[2] = f2bf(a2.z); c1v[3] = f2bf(a2.w);
        c1v[4] = f2bf(a3.x); c1v[5] = f2bf(a3.y); c1v[6] = f2bf(a3.z); c1v[7] = f2bf(a3.w);
        *(u16x8*)&As[ar * 64 + ((ac2    ) ^ asw) * 8] = c0v;
        *(u16x8*)&As[ar * 64 + ((ac2 + 1) ^ asw) * 8] = c1v;
        __syncthreads();
        #pragma unroll
        for (int kk = 0; kk < 2; ++kk) {
            const int chnk = ((kk * 4 + (lane >> 4)) ^ (fr & 7)) * 8;
            bf16x8 af[2], bfv[2];
            #pragma unroll
            for (int mi = 0; mi < 2; ++mi)
                af[mi] = *(const bf16x8*)&As[(wr * 32 + mi * 16 + fr) * 64 + chnk];
            #pragma unroll
            for (int ni = 0; ni < 2; ++ni)
                bfv[ni] = *(const bf16x8*)&Bs[(wc * 32 + ni * 16 + fr) * 64 + chnk];
            #pragma unroll
            for (int mi = 0; mi < 2; ++mi)
                #pragma unroll
                for (int ni = 0; ni < 2; ++ni)
                    acc[mi][ni] = __builtin_amdgcn_mfma_f32_16x16x32_bf16(
                        af[mi], bfv[ni], acc[mi][ni], 0, 0, 0);
        }
    }

    const int orow = (lane >> 4) * 4, ocol = lane & 15;
    #pragma unroll
    for (int mi = 0; mi < 2; ++mi) {
        #pragma unroll
        for (int ni = 0; ni < 2; ++ni) {
            const int cg = col0 + wc * 32 + ni * 16 + ocol;
            #pragma unroll
            for (int j = 0; j < 4; ++j) {
                const int rg = row0 + wr * 32 + mi * 16 + orow + j;
                const float v = acc[mi][ni][j];
                if (cg < 256) {
                    const int h = cg >> 6, kk = (cg >> 5) & 1;
                    const int q4p = (cg >> 3) & 3, el = cg & 7;
                    Qf[((((size_t)(rg >> 4) * 4 + h) * 2 + kk) * 64
                        + q4p * 16 + (rg & 15)) * 8 + el] = f2bf(sanef(v));
                } else if (cg < 320) {
                    const int ck = cg - 256;
                    const int kk = ck >> 5, q4p = (ck >> 3) & 3, el = ck & 7;
                    Kf[(((size_t)(rg >> 4) * 2 + kk) * 64
                        + q4p * 16 + (rg & 15)) * 8 + el] = f2bf(sanef(v));
                } else if (cg < 324) {
                    Wo[(size_t)rg * 4 + (cg - 320)] = sanef(sigm(v + bw[cg - 320]));
                }
            }
        }
    }
}

// ============ Kernel 3: score compute only, 1-wave blocks, 64x64 wave tile ============
// 4224 blocks (8x528 XCD-chunked): wave = one 64-row half of a lower 128x64
// tile, ALL 64 cols. kf[2][4] reused over 2x outputs; 8 MFMAs (4 indep chains)
// per h-step. VGPR ~110 under the (64,4)=128 cap -> hoisting headroom.
__global__ __launch_bounds__(64, 4)
void score_comp(const unsigned short* __restrict__ Qf,   // fragment-order, 4MB
                const unsigned short* __restrict__ Kf,   // fragment-order, 1MB
                const float* __restrict__ Wo,            // [8192][4] = sigmoid(w)
                const float* __restrict__ ib,
                float* __restrict__ out)
{
    const int bid = blockIdx.x;
    const int v   = (bid & 7) * 528 + (bid >> 3);  // 4224 = 8*528, bijective
    const int half = v & 1, tile = v >> 1;         // tile in [0,2112)
    const int b = tile / 1056, u = tile % 1056;
    const int lane = threadIdx.x;

    int it = (int)((sqrtf(4.f * u + 1.f) - 1.f) * 0.5f);
    while (it * it + it > u) --it;
    while ((it + 1) * (it + 1) + (it + 1) <= u) ++it;
    const int jt = u - it * it - it;

    const int row0 = it * 128 + half * 64;         // this wave's 64 rows
    const int col0 = jt * 64;                      // full 64 cols
    const int brow = b * TSEQ + row0;
    const int fr = lane & 15, q4 = lane >> 4;

    const int Rq = brow >> 4;                      // +mi
    const int Rk = (b * TSEQ + col0) >> 4;         // +ni
    const unsigned short* Qp = Qf + (size_t)Rq * 4096 + lane * 8;  // +(mi*8+h*2+kk)*512
    const unsigned short* Kp = Kf + (size_t)Rk * 1024 + lane * 8;  // +(ni*1024 + kk*512)... see below
    const float* Wop = Wo + (size_t)(brow + q4 * 4) * 4;           // +[(mi*16+j)*4+h]
    const float C1 = -SCALE * LOG2E;
    const bool diag = (col0 + 63 > row0);
    const size_t obase = ((size_t)brow) * TSEQ + col0;

    // Kf index for K-row-group (Rk+ni), slice kk: ((Rk+ni)*2 + kk)*512
    bf16x8 kf[2][4];                               // [kk][ni]
    #pragma unroll
    for (int ni = 0; ni < 4; ++ni)
        #pragma unroll
        for (int kk = 0; kk < 2; ++kk)
            kf[kk][ni] = *(const bf16x8*)(Kp + ((size_t)ni * 2 + kk) * 512);

    #pragma unroll
    for (int mi = 0; mi < 4; ++mi) {
        const int r0 = mi * 16 + q4 * 4;
        f32x4 fin[4];
        #pragma unroll
        for (int ni = 0; ni < 4; ++ni) fin[ni] = (f32x4){0.f, 0.f, 0.f, 0.f};

        #pragma unroll
        for (int h = 0; h < 4; ++h) {
            const bf16x8 q0 = *(const bf16x8*)(Qp + (size_t)(mi * 8 + h * 2) * 512);
            const bf16x8 q1 = *(const bf16x8*)(Qp + (size_t)(mi * 8 + h * 2 + 1) * 512);
            f32x4 acc[4];
            #pragma unroll
            for (int ni = 0; ni < 4; ++ni) acc[ni] = (f32x4){0.f, 0.f, 0.f, 0.f};
            #pragma unroll
            for (int ni = 0; ni < 4; ++ni) {
                acc[ni] = __builtin_amdgcn_mfma_f32_16x16x32_bf16(q0, kf[0][ni], acc[ni], 0, 0, 0);
                acc[ni] = __builtin_amdgcn_mfma_f32_16x16x32_bf16(q1, kf[1][ni], acc[ni], 0, 0, 0);
            }
            const float c0 = -ib[h] * LOG2E;
            #pragma unroll
            for (int j = 0; j < 4; ++j) {
                const float wsj = Wop[(mi * 16 + j) * 4 + h];
                #pragma unroll
                for (int ni = 0; ni < 4; ++ni)
                    fin[ni][j] += __builtin_amdgcn_rcpf(1.0f + EXP2(fmaf(acc[ni][j], C1, c0))) * wsj;
            }
        }

        #pragma unroll
        for (int j = 0; j < 4; ++j) {
            const int rl = r0 + j;
            #pragma unroll
            for (int ni = 0; ni < 4; ++ni) {
                const int cl = ni * 16 + fr;
                float vv = fin[ni][j];
                if (diag && (col0 + cl > row0 + rl)) vv = NEG_HUGE;
                out[obase + (size_t)rl * TSEQ + cl] = vv;
            }
        }
    }
}

extern "C" void kernel_launch(void* const* d_in, const int* in_sizes, int n_in,
                              void* d_out, int out_size, void* d_ws, size_t ws_size,
                              hipStream_t stream)
{
    const float* x  = (const float*)d_in[0];
    const float* Wq = (const float*)d_in[1];
    const float* Wk = (const float*)d_in[2];
    const float* Ww = (const float*)d_in[3];
    const float* bw = (const float*)d_in[4];
    const float* ib = (const float*)d_in[5];
    float* out = (float*)d_out;

    unsigned short* Wc = (unsigned short*)d_ws;            // 1.5 MB
    unsigned short* Qf = Wc + (size_t)384 * HID;           // 4 MB (fragment order)
    unsigned short* Kf = Qf + (size_t)NROW * 256;          // 1 MB (fragment order)
    float*          Wo = (float*)(Kf + (size_t)NROW * 64); // 128 KB

    score_fill<<<dim3(496, NB), dim3(256), 0, stream>>>(out);
    cvt_w<<<dim3(384), dim3(256), 0, stream>>>(Wq, Wk, Ww, Wc);
    proj_mfma<<<dim3(768), dim3(256), 0, stream>>>(x, Wc, bw, Qf, Kf, Wo);
    score_comp<<<dim3(4224), dim3(64), 0, stream>>>(Qf, Kf, Wo, ib, out);
}

// Round 19
// 75.486 us; speedup vs baseline: 1.1557x; 1.1557x over previous
//
#include <hip/hip_runtime.h>
#include <cmath>

typedef __attribute__((ext_vector_type(4))) float f32x4;
typedef __attribute__((ext_vector_type(8))) short bf16x8;
typedef __attribute__((ext_vector_type(8))) unsigned short u16x8;

#define TSEQ 4096
#define NB 2
#define HID 2048
#define DD 64
#define NH 4
#define NROW 8192
#define SCALE 0.125f
#define NEG_HUGE -3.3e38f
#define LOG2E 1.4426950408889634f

#if __has_builtin(__builtin_amdgcn_exp2f)
#define EXP2(x) __builtin_amdgcn_exp2f(x)
#else
#define EXP2(x) exp2f(x)
#endif

__device__ __forceinline__ float sanef(float v) {
    return fminf(fmaxf(v, -3.3e38f), 3.3e38f);   // NaN->-3.3e38, +/-inf clamped
}
__device__ __forceinline__ unsigned short f2bf(float f) {  // RNE fp32->bf16
    unsigned int u = __float_as_uint(f);
    unsigned int r = u + 0x7FFF + ((u >> 16) & 1);
    return (unsigned short)(r >> 16);
}
__device__ __forceinline__ float sigm(float z) {
    return 1.0f / (1.0f + __expf(-z));
}
__device__ __forceinline__ void gload16(const unsigned short* g, unsigned short* l) {
    __builtin_amdgcn_global_load_lds(
        (const __attribute__((address_space(1))) void*)g,
        (__attribute__((address_space(3))) void*)l, 16, 0, 0);
}

// Fragment-order layouts (score reads = base + lane*8 + const, 1KB/wave):
//   Qf[(((row>>4)*4 + h)*2 + kk)*512 + (q4*16 + (row&15))*8 + el]
//   Kf[(((row>>4)*2 + kk))*512 + (q4*16 + (row&15))*8 + el]

// ============ Kernel 1: weight concat [384][2048] bf16 ============
__global__ __launch_bounds__(256)
void cvt_w(const float* __restrict__ Wq, const float* __restrict__ Wk,
           const float* __restrict__ Ww, unsigned short* __restrict__ Wc)
{
    const int r = blockIdx.x;
    const int c0 = threadIdx.x * 8;
    const float* src = nullptr;
    if (r < 256)      src = Wq + (size_t)r * HID;
    else if (r < 320) src = Wk + (size_t)(r - 256) * HID;
    else if (r < 324) src = Ww + (size_t)(r - 320) * HID;
    u16x8 o = {0, 0, 0, 0, 0, 0, 0, 0};
    if (src) {
        const float4 a = *(const float4*)(src + c0);
        const float4 b = *(const float4*)(src + c0 + 4);
        o[0] = f2bf(a.x); o[1] = f2bf(a.y); o[2] = f2bf(a.z); o[3] = f2bf(a.w);
        o[4] = f2bf(b.x); o[5] = f2bf(b.y); o[6] = f2bf(b.z); o[7] = f2bf(b.w);
    }
    *(u16x8*)(Wc + (size_t)r * HID + c0) = o;
}

// ============ Kernel 2: fused cvt_x + projection GEMM, 64x64 tiles ============
// r9/r15 known-good main loop; epilogue writes Q/K in MFMA-fragment order.
__global__ __launch_bounds__(256)
void proj_mfma(const float* __restrict__ x,
               const unsigned short* __restrict__ Wc,
               const float* __restrict__ bw,
               unsigned short* __restrict__ Qf,
               unsigned short* __restrict__ Kf,
               float* __restrict__ Wo)
{
    __shared__ unsigned short As[64 * 64];    // 8 KB
    __shared__ unsigned short Bs[64 * 64];    // 8 KB
    const int bid = blockIdx.x;
    const int w   = (bid & 7) * 96 + (bid >> 3);     // 768 = 8*96, bijective
    const int row0 = (w / 6) * 64;
    const int col0 = (w % 6) * 64;

    const int tid  = threadIdx.x;
    const int lane = tid & 63, wid = tid >> 6;
    const int wr = wid >> 1, wc = wid & 1;           // wave tile 32x32
    const int fr = lane & 15;

    const int ar = tid >> 2, ac2 = (tid & 3) * 2, asw = ar & 7;
    const float* Axg = x + (size_t)(row0 + ar) * HID + (tid & 3) * 16;

    const int sr = tid >> 3;
    const int scs = ((tid & 7) ^ (sr & 7)) * 8;
    const unsigned short* Bg = Wc + (size_t)(col0 + sr) * HID + scs;

    f32x4 acc[2][2];
    #pragma unroll
    for (int i = 0; i < 2; ++i)
        #pragma unroll
        for (int j = 0; j < 2; ++j) acc[i][j] = (f32x4){0.f, 0.f, 0.f, 0.f};

    for (int kt = 0; kt < HID; kt += 64) {
        const float4 a0 = *(const float4*)(Axg + kt);
        const float4 a1 = *(const float4*)(Axg + kt + 4);
        const float4 a2 = *(const float4*)(Axg + kt + 8);
        const float4 a3 = *(const float4*)(Axg + kt + 12);
        __syncthreads();
        #pragma unroll
        for (int c2 = 0; c2 < 2; ++c2)
            gload16(Bg + (size_t)c2 * 32 * HID + kt, &Bs[wid * 512 + c2 * 2048]);
        u16x8 c0v, c1v;
        c0v[0] = f2bf(a0.x); c0v[1] = f2bf(a0.y); c0v[2] = f2bf(a0.z); c0v[3] = f2bf(a0.w);
        c0v[4] = f2bf(a1.x); c0v[5] = f2bf(a1.y); c0v[6] = f2bf(a1.z); c0v[7] = f2bf(a1.w);
        c1v[0] = f2bf(a2.x); c1v[1] = f2bf(a2.y); c1v[2] = f2bf(a2.z); c1v[3] = f2bf(a2.w);
        c1v[4] = f2bf(a3.x); c1v[5] = f2bf(a3.y); c1v[6] = f2bf(a3.z); c1v[7] = f2bf(a3.w);
        *(u16x8*)&As[ar * 64 + ((ac2    ) ^ asw) * 8] = c0v;
        *(u16x8*)&As[ar * 64 + ((ac2 + 1) ^ asw) * 8] = c1v;
        __syncthreads();
        #pragma unroll
        for (int kk = 0; kk < 2; ++kk) {
            const int chnk = ((kk * 4 + (lane >> 4)) ^ (fr & 7)) * 8;
            bf16x8 af[2], bfv[2];
            #pragma unroll
            for (int mi = 0; mi < 2; ++mi)
                af[mi] = *(const bf16x8*)&As[(wr * 32 + mi * 16 + fr) * 64 + chnk];
            #pragma unroll
            for (int ni = 0; ni < 2; ++ni)
                bfv[ni] = *(const bf16x8*)&Bs[(wc * 32 + ni * 16 + fr) * 64 + chnk];
            #pragma unroll
            for (int mi = 0; mi < 2; ++mi)
                #pragma unroll
                for (int ni = 0; ni < 2; ++ni)
                    acc[mi][ni] = __builtin_amdgcn_mfma_f32_16x16x32_bf16(
                        af[mi], bfv[ni], acc[mi][ni], 0, 0, 0);
        }
    }

    const int orow = (lane >> 4) * 4, ocol = lane & 15;
    #pragma unroll
    for (int mi = 0; mi < 2; ++mi) {
        #pragma unroll
        for (int ni = 0; ni < 2; ++ni) {
            const int cg = col0 + wc * 32 + ni * 16 + ocol;
            #pragma unroll
            for (int j = 0; j < 4; ++j) {
                const int rg = row0 + wr * 32 + mi * 16 + orow + j;
                const float v = acc[mi][ni][j];
                if (cg < 256) {
                    const int h = cg >> 6, kk = (cg >> 5) & 1;
                    const int q4p = (cg >> 3) & 3, el = cg & 7;
                    Qf[((((size_t)(rg >> 4) * 4 + h) * 2 + kk) * 64
                        + q4p * 16 + (rg & 15)) * 8 + el] = f2bf(sanef(v));
                } else if (cg < 320) {
                    const int ck = cg - 256;
                    const int kk = ck >> 5, q4p = (ck >> 3) & 3, el = ck & 7;
                    Kf[(((size_t)(rg >> 4) * 2 + kk) * 64
                        + q4p * 16 + (rg & 15)) * 8 + el] = f2bf(sanef(v));
                } else if (cg < 324) {
                    Wo[(size_t)rg * 4 + (cg - 320)] = sanef(sigm(v + bw[cg - 320]));
                }
            }
        }
    }
}

// ============ Kernel 3: merged scores (r17 structure) + mi-level Q dbuf ============
// 9440 = 8*1180 1-wave blocks; fill merged (r18 proved split = +10us serial).
// NEW: r7-style static double-buffer qa/qb at mi granularity — 8 Q loads
// issued one full mi-group (~600cyc) before use; exposed L3 latency ~1x/wave.
__global__ __launch_bounds__(64, 4)
void score_all(const unsigned short* __restrict__ Qf,   // fragment-order, 4MB
               const unsigned short* __restrict__ Kf,   // fragment-order, 1MB
               const float* __restrict__ Wo,            // [8192][4] = sigmoid(w)
               const float* __restrict__ ib,
               float* __restrict__ out)
{
    const int bid = blockIdx.x;
    const int xcd = bid & 7, wx = bid >> 3;        // wx in [0,1180)
    const int lane = threadIdx.x;

    if (wx >= 1056) {                // ---- fill: strict-upper 128x128 ----
        const int v = xcd * 124 + (wx - 1056);     // [0,992)
        const int b = v / 496, u = v % 496;
        int p = (int)((sqrtf(8.f * u + 1.f) + 1.f) * 0.5f);
        while (p * (p - 1) / 2 > u) --p;
        while ((p + 1) * p / 2 <= u) ++p;
        const int q = u - p * (p - 1) / 2;
        const size_t obase = ((size_t)b * TSEQ + (size_t)q * 128) * TSEQ + (size_t)p * 128;
        float4* po = (float4*)(out + obase + (size_t)(lane >> 5) * TSEQ) + (lane & 31);
        const float4 nh = make_float4(NEG_HUGE, NEG_HUGE, NEG_HUGE, NEG_HUGE);
        #pragma unroll 8
        for (int i = 0; i < 64; ++i) {
            *po = nh;
            po += 2 * TSEQ / 4;
        }
        return;
    }

    // ---- compute: quarter (64x32) of a lower 128x64 tile ----
    const int v = xcd * 1056 + wx;                 // [0,8448)
    const int tile = v >> 2, s = v & 3;
    const int wr = s >> 1, wc = s & 1;
    const int b = tile / 1056, u = tile % 1056;
    int it = (int)((sqrtf(4.f * u + 1.f) - 1.f) * 0.5f);
    while (it * it + it > u) --it;
    while ((it + 1) * (it + 1) + (it + 1) <= u) ++it;
    const int jt = u - it * it - it;

    const int row0 = it * 128, col0 = jt * 64;
    const int brow = b * TSEQ + row0;
    const int fr = lane & 15, q4 = lane >> 4;

    const int Rq = (brow + wr * 64) >> 4;
    const int Rk = (b * TSEQ + col0 + wc * 32) >> 4;
    const unsigned short* Qp = Qf + (size_t)Rq * 4096 + lane * 8;   // +(mi*8 + h*2 + kk)*512
    const unsigned short* Kp = Kf + (size_t)Rk * 1024 + lane * 8;   // +(ni*2 + kk)*512
    const float* Wop = Wo + (size_t)(brow + wr * 64 + q4 * 4) * 4;  // +[(mi*16+j)*4+h]
    const float C1 = -SCALE * LOG2E;
    const bool diag = (col0 + 63 > row0);
    const size_t obase = ((size_t)brow) * TSEQ + col0;

    bf16x8 kf[2][2];                               // [kk][ni], reused all mi,h
    #pragma unroll
    for (int kk = 0; kk < 2; ++kk)
        #pragma unroll
        for (int ni = 0; ni < 2; ++ni)
            kf[kk][ni] = *(const bf16x8*)(Kp + (size_t)(ni * 2 + kk) * 512);

#define LOADQ(QV, MI)                                                         \
    _Pragma("unroll")                                                         \
    for (int f = 0; f < 8; ++f)                                               \
        QV[f] = *(const bf16x8*)(Qp + (size_t)((MI) * 8 + f) * 512);

#define FOLD(QV, MI)                                                          \
    {                                                                         \
        const int r0 = wr * 64 + (MI) * 16 + q4 * 4;                          \
        f32x4 fin0 = {0.f, 0.f, 0.f, 0.f}, fin1 = {0.f, 0.f, 0.f, 0.f};       \
        _Pragma("unroll")                                                     \
        for (int h = 0; h < 4; ++h) {                                         \
            f32x4 a0 = {0.f, 0.f, 0.f, 0.f}, a1 = {0.f, 0.f, 0.f, 0.f};       \
            a0 = __builtin_amdgcn_mfma_f32_16x16x32_bf16(QV[h*2],   kf[0][0], a0, 0, 0, 0); \
            a0 = __builtin_amdgcn_mfma_f32_16x16x32_bf16(QV[h*2+1], kf[1][0], a0, 0, 0, 0); \
            a1 = __builtin_amdgcn_mfma_f32_16x16x32_bf16(QV[h*2],   kf[0][1], a1, 0, 0, 0); \
            a1 = __builtin_amdgcn_mfma_f32_16x16x32_bf16(QV[h*2+1], kf[1][1], a1, 0, 0, 0); \
            const float c0 = -ib[h] * LOG2E;                                  \
            _Pragma("unroll")                                                 \
            for (int j = 0; j < 4; ++j) {                                     \
                const float wsj = Wop[((MI) * 16 + j) * 4 + h];               \
                fin0[j] += __builtin_amdgcn_rcpf(1.0f + EXP2(fmaf(a0[j], C1, c0))) * wsj; \
                fin1[j] += __builtin_amdgcn_rcpf(1.0f + EXP2(fmaf(a1[j], C1, c0))) * wsj; \
            }                                                                 \
        }                                                                     \
        _Pragma("unroll")                                                     \
        for (int j = 0; j < 4; ++j) {                                         \
            const int rl = r0 + j;                                            \
            const int cl0 = wc * 32 + fr, cl1 = cl0 + 16;                     \
            float v0 = fin0[j], v1 = fin1[j];                                 \
            if (diag) {                                                       \
                if (col0 + cl0 > row0 + rl) v0 = NEG_HUGE;                    \
                if (col0 + cl1 > row0 + rl) v1 = NEG_HUGE;                    \
            }                                                                 \
            out[obase + (size_t)rl * TSEQ + cl0] = v0;                        \
            out[obase + (size_t)rl * TSEQ + cl1] = v1;                        \
        }                                                                     \
    }

    bf16x8 qa[8], qb[8];
    LOADQ(qa, 0);
    LOADQ(qb, 1);
    FOLD(qa, 0);
    LOADQ(qa, 2);
    FOLD(qb, 1);
    LOADQ(qb, 3);
    FOLD(qa, 2);
    FOLD(qb, 3);
#undef LOADQ
#undef FOLD
}

extern "C" void kernel_launch(void* const* d_in, const int* in_sizes, int n_in,
                              void* d_out, int out_size, void* d_ws, size_t ws_size,
                              hipStream_t stream)
{
    const float* x  = (const float*)d_in[0];
    const float* Wq = (const float*)d_in[1];
    const float* Wk = (const float*)d_in[2];
    const float* Ww = (const float*)d_in[3];
    const float* bw = (const float*)d_in[4];
    const float* ib = (const float*)d_in[5];
    float* out = (float*)d_out;

    unsigned short* Wc = (unsigned short*)d_ws;            // 1.5 MB
    unsigned short* Qf = Wc + (size_t)384 * HID;           // 4 MB (fragment order)
    unsigned short* Kf = Qf + (size_t)NROW * 256;          // 1 MB (fragment order)
    float*          Wo = (float*)(Kf + (size_t)NROW * 64); // 128 KB

    cvt_w<<<dim3(384), dim3(256), 0, stream>>>(Wq, Wk, Ww, Wc);
    proj_mfma<<<dim3(768), dim3(256), 0, stream>>>(x, Wc, bw, Qf, Kf, Wo);
    score_all<<<dim3(9440), dim3(64), 0, stream>>>(Qf, Kf, Wo, ib, out);
}

// Round 20
// 73.391 us; speedup vs baseline: 1.1887x; 1.0286x over previous
//
#include <hip/hip_runtime.h>
#include <cmath>

typedef __attribute__((ext_vector_type(4))) float f32x4;
typedef __attribute__((ext_vector_type(8))) short bf16x8;
typedef __attribute__((ext_vector_type(8))) unsigned short u16x8;

#define TSEQ 4096
#define NB 2
#define HID 2048
#define DD 64
#define NH 4
#define NROW 8192
#define SCALE 0.125f
#define NEG_HUGE -3.3e38f
#define LOG2E 1.4426950408889634f

#if __has_builtin(__builtin_amdgcn_exp2f)
#define EXP2(x) __builtin_amdgcn_exp2f(x)
#else
#define EXP2(x) exp2f(x)
#endif

__device__ __forceinline__ float sanef(float v) {
    return fminf(fmaxf(v, -3.3e38f), 3.3e38f);   // NaN->-3.3e38, +/-inf clamped
}
__device__ __forceinline__ unsigned short f2bf(float f) {  // RNE fp32->bf16
    unsigned int u = __float_as_uint(f);
    unsigned int r = u + 0x7FFF + ((u >> 16) & 1);
    return (unsigned short)(r >> 16);
}
__device__ __forceinline__ float sigm(float z) {
    return 1.0f / (1.0f + __expf(-z));
}
__device__ __forceinline__ void gload16(const unsigned short* g, unsigned short* l) {
    __builtin_amdgcn_global_load_lds(
        (const __attribute__((address_space(1))) void*)g,
        (__attribute__((address_space(3))) void*)l, 16, 0, 0);
}

// Fragment-order layouts (score reads = base + lane*8 + const, 1KB/wave):
//   Qf[(((row>>4)*4 + h)*2 + kk)*512 + (q4*16 + (row&15))*8 + el]
//   Kf[(((row>>4)*2 + kk))*512 + (q4*16 + (row&15))*8 + el]

// ============ Kernel 1: weight concat [384][2048] bf16 ============
__global__ __launch_bounds__(256)
void cvt_w(const float* __restrict__ Wq, const float* __restrict__ Wk,
           const float* __restrict__ Ww, unsigned short* __restrict__ Wc)
{
    const int r = blockIdx.x;
    const int c0 = threadIdx.x * 8;
    const float* src = nullptr;
    if (r < 256)      src = Wq + (size_t)r * HID;
    else if (r < 320) src = Wk + (size_t)(r - 256) * HID;
    else if (r < 324) src = Ww + (size_t)(r - 320) * HID;
    u16x8 o = {0, 0, 0, 0, 0, 0, 0, 0};
    if (src) {
        const float4 a = *(const float4*)(src + c0);
        const float4 b = *(const float4*)(src + c0 + 4);
        o[0] = f2bf(a.x); o[1] = f2bf(a.y); o[2] = f2bf(a.z); o[3] = f2bf(a.w);
        o[4] = f2bf(b.x); o[5] = f2bf(b.y); o[6] = f2bf(b.z); o[7] = f2bf(b.w);
    }
    *(u16x8*)(Wc + (size_t)r * HID + c0) = o;
}

// ============ Kernel 2: fused cvt_x + projection GEMM, 64x64 tiles ============
// r9/r15 known-good main loop; epilogue writes Q/K in MFMA-fragment order.
__global__ __launch_bounds__(256)
void proj_mfma(const float* __restrict__ x,
               const unsigned short* __restrict__ Wc,
               const float* __restrict__ bw,
               unsigned short* __restrict__ Qf,
               unsigned short* __restrict__ Kf,
               float* __restrict__ Wo)
{
    __shared__ unsigned short As[64 * 64];    // 8 KB
    __shared__ unsigned short Bs[64 * 64];    // 8 KB
    const int bid = blockIdx.x;
    const int w   = (bid & 7) * 96 + (bid >> 3);     // 768 = 8*96, bijective
    const int row0 = (w / 6) * 64;
    const int col0 = (w % 6) * 64;

    const int tid  = threadIdx.x;
    const int lane = tid & 63, wid = tid >> 6;
    const int wr = wid >> 1, wc = wid & 1;           // wave tile 32x32
    const int fr = lane & 15;

    const int ar = tid >> 2, ac2 = (tid & 3) * 2, asw = ar & 7;
    const float* Axg = x + (size_t)(row0 + ar) * HID + (tid & 3) * 16;

    const int sr = tid >> 3;
    const int scs = ((tid & 7) ^ (sr & 7)) * 8;
    const unsigned short* Bg = Wc + (size_t)(col0 + sr) * HID + scs;

    f32x4 acc[2][2];
    #pragma unroll
    for (int i = 0; i < 2; ++i)
        #pragma unroll
        for (int j = 0; j < 2; ++j) acc[i][j] = (f32x4){0.f, 0.f, 0.f, 0.f};

    for (int kt = 0; kt < HID; kt += 64) {
        const float4 a0 = *(const float4*)(Axg + kt);
        const float4 a1 = *(const float4*)(Axg + kt + 4);
        const float4 a2 = *(const float4*)(Axg + kt + 8);
        const float4 a3 = *(const float4*)(Axg + kt + 12);
        __syncthreads();
        #pragma unroll
        for (int c2 = 0; c2 < 2; ++c2)
            gload16(Bg + (size_t)c2 * 32 * HID + kt, &Bs[wid * 512 + c2 * 2048]);
        u16x8 c0v, c1v;
        c0v[0] = f2bf(a0.x); c0v[1] = f2bf(a0.y); c0v[2] = f2bf(a0.z); c0v[3] = f2bf(a0.w);
        c0v[4] = f2bf(a1.x); c0v[5] = f2bf(a1.y); c0v[6] = f2bf(a1.z); c0v[7] = f2bf(a1.w);
        c1v[0] = f2bf(a2.x); c1v[1] = f2bf(a2.y); c1v[2] = f2bf(a2.z); c1v[3] = f2bf(a2.w);
        c1v[4] = f2bf(a3.x); c1v[5] = f2bf(a3.y); c1v[6] = f2bf(a3.z); c1v[7] = f2bf(a3.w);
        *(u16x8*)&As[ar * 64 + ((ac2    ) ^ asw) * 8] = c0v;
        *(u16x8*)&As[ar * 64 + ((ac2 + 1) ^ asw) * 8] = c1v;
        __syncthreads();
        #pragma unroll
        for (int kk = 0; kk < 2; ++kk) {
            const int chnk = ((kk * 4 + (lane >> 4)) ^ (fr & 7)) * 8;
            bf16x8 af[2], bfv[2];
            #pragma unroll
            for (int mi = 0; mi < 2; ++mi)
                af[mi] = *(const bf16x8*)&As[(wr * 32 + mi * 16 + fr) * 64 + chnk];
            #pragma unroll
            for (int ni = 0; ni < 2; ++ni)
                bfv[ni] = *(const bf16x8*)&Bs[(wc * 32 + ni * 16 + fr) * 64 + chnk];
            #pragma unroll
            for (int mi = 0; mi < 2; ++mi)
                #pragma unroll
                for (int ni = 0; ni < 2; ++ni)
                    acc[mi][ni] = __builtin_amdgcn_mfma_f32_16x16x32_bf16(
                        af[mi], bfv[ni], acc[mi][ni], 0, 0, 0);
        }
    }

    const int orow = (lane >> 4) * 4, ocol = lane & 15;
    #pragma unroll
    for (int mi = 0; mi < 2; ++mi) {
        #pragma unroll
        for (int ni = 0; ni < 2; ++ni) {
            const int cg = col0 + wc * 32 + ni * 16 + ocol;
            #pragma unroll
            for (int j = 0; j < 4; ++j) {
                const int rg = row0 + wr * 32 + mi * 16 + orow + j;
                const float v = acc[mi][ni][j];
                if (cg < 256) {
                    const int h = cg >> 6, kk = (cg >> 5) & 1;
                    const int q4p = (cg >> 3) & 3, el = cg & 7;
                    Qf[((((size_t)(rg >> 4) * 4 + h) * 2 + kk) * 64
                        + q4p * 16 + (rg & 15)) * 8 + el] = f2bf(sanef(v));
                } else if (cg < 320) {
                    const int ck = cg - 256;
                    const int kk = ck >> 5, q4p = (ck >> 3) & 3, el = ck & 7;
                    Kf[(((size_t)(rg >> 4) * 2 + kk) * 64
                        + q4p * 16 + (rg & 15)) * 8 + el] = f2bf(sanef(v));
                } else if (cg < 324) {
                    Wo[(size_t)rg * 4 + (cg - 320)] = sanef(sigm(v + bw[cg - 320]));
                }
            }
        }
    }
}

// ============ Kernel 3: merged scores (r17 loop) + LDS-staged wide stores ============
// 9440 = 8*1180 1-wave blocks. NEW: per-mi store transpose through a 16x36
// padded LDS buffer (2-way alias = free, m136) -> 2 global_store_dwordx4 per
// lane per mi (8 rows x 128B contiguous per instr) instead of 8 scattered
// dword stores (4 rows x 64B). Same-wave ds ordering needs no barrier.
__global__ __launch_bounds__(64, 4)
void score_all(const unsigned short* __restrict__ Qf,   // fragment-order, 4MB
               const unsigned short* __restrict__ Kf,   // fragment-order, 1MB
               const float* __restrict__ Wo,            // [8192][4] = sigmoid(w)
               const float* __restrict__ ib,
               float* __restrict__ out)
{
    __shared__ float sbuf[16 * 36];                // 2.3 KB, store transpose
    const int bid = blockIdx.x;
    const int xcd = bid & 7, wx = bid >> 3;        // wx in [0,1180)
    const int lane = threadIdx.x;

    if (wx >= 1056) {                // ---- fill: strict-upper 128x128 ----
        const int v = xcd * 124 + (wx - 1056);     // [0,992)
        const int b = v / 496, u = v % 496;
        int p = (int)((sqrtf(8.f * u + 1.f) + 1.f) * 0.5f);
        while (p * (p - 1) / 2 > u) --p;
        while ((p + 1) * p / 2 <= u) ++p;
        const int q = u - p * (p - 1) / 2;
        const size_t obase = ((size_t)b * TSEQ + (size_t)q * 128) * TSEQ + (size_t)p * 128;
        float4* po = (float4*)(out + obase + (size_t)(lane >> 5) * TSEQ) + (lane & 31);
        const float4 nh = make_float4(NEG_HUGE, NEG_HUGE, NEG_HUGE, NEG_HUGE);
        #pragma unroll 8
        for (int i = 0; i < 64; ++i) {
            *po = nh;
            po += 2 * TSEQ / 4;
        }
        return;
    }

    // ---- compute: quarter (64x32) of a lower 128x64 tile ----
    const int v = xcd * 1056 + wx;                 // [0,8448)
    const int tile = v >> 2, s = v & 3;
    const int wr = s >> 1, wc = s & 1;
    const int b = tile / 1056, u = tile % 1056;
    int it = (int)((sqrtf(4.f * u + 1.f) - 1.f) * 0.5f);
    while (it * it + it > u) --it;
    while ((it + 1) * (it + 1) + (it + 1) <= u) ++it;
    const int jt = u - it * it - it;

    const int row0 = it * 128, col0 = jt * 64;
    const int brow = b * TSEQ + row0;
    const int fr = lane & 15, q4 = lane >> 4;

    const int Rq = (brow + wr * 64) >> 4;
    const int Rk = (b * TSEQ + col0 + wc * 32) >> 4;
    const unsigned short* Qp = Qf + (size_t)Rq * 4096 + lane * 8;   // +(mi*8 + h*2 + kk)*512
    const unsigned short* Kp = Kf + (size_t)Rk * 1024 + lane * 8;   // +(ni*2 + kk)*512
    const float* Wop = Wo + (size_t)(brow + wr * 64 + q4 * 4) * 4;  // +[(mi*16+j)*4+h]
    const float C1 = -SCALE * LOG2E;
    const bool diag = (col0 + 63 > row0);

    bf16x8 kf[2][2];                               // [kk][ni], reused all mi,h
    #pragma unroll
    for (int kk = 0; kk < 2; ++kk)
        #pragma unroll
        for (int ni = 0; ni < 2; ++ni)
            kf[kk][ni] = *(const bf16x8*)(Kp + (size_t)(ni * 2 + kk) * 512);

    const int cl0 = wc * 32 + fr, cl1 = cl0 + 16;

    #pragma unroll
    for (int mi = 0; mi < 4; ++mi) {
        const int r0 = wr * 64 + mi * 16 + q4 * 4;
        f32x4 fin0 = {0.f, 0.f, 0.f, 0.f}, fin1 = {0.f, 0.f, 0.f, 0.f};
        #pragma unroll
        for (int h = 0; h < 4; ++h) {
            const bf16x8 q0 = *(const bf16x8*)(Qp + (size_t)(mi * 8 + h * 2) * 512);
            const bf16x8 q1 = *(const bf16x8*)(Qp + (size_t)(mi * 8 + h * 2 + 1) * 512);
            f32x4 a0 = {0.f, 0.f, 0.f, 0.f}, a1 = {0.f, 0.f, 0.f, 0.f};
            a0 = __builtin_amdgcn_mfma_f32_16x16x32_bf16(q0, kf[0][0], a0, 0, 0, 0);
            a0 = __builtin_amdgcn_mfma_f32_16x16x32_bf16(q1, kf[1][0], a0, 0, 0, 0);
            a1 = __builtin_amdgcn_mfma_f32_16x16x32_bf16(q0, kf[0][1], a1, 0, 0, 0);
            a1 = __builtin_amdgcn_mfma_f32_16x16x32_bf16(q1, kf[1][1], a1, 0, 0, 0);
            const float c0 = -ib[h] * LOG2E;
            #pragma unroll
            for (int j = 0; j < 4; ++j) {
                const float wsj = Wop[(mi * 16 + j) * 4 + h];
                fin0[j] += __builtin_amdgcn_rcpf(1.0f + EXP2(fmaf(a0[j], C1, c0))) * wsj;
                fin1[j] += __builtin_amdgcn_rcpf(1.0f + EXP2(fmaf(a1[j], C1, c0))) * wsj;
            }
        }

        // ---- mask + stage to LDS (rows mi*16..mi*16+15 of this wave's 64) ----
        #pragma unroll
        for (int j = 0; j < 4; ++j) {
            const int rl = r0 + j;
            float v0 = fin0[j], v1 = fin1[j];
            if (diag) {
                if (col0 + cl0 > row0 + rl) v0 = NEG_HUGE;
                if (col0 + cl1 > row0 + rl) v1 = NEG_HUGE;
            }
            sbuf[(q4 * 4 + j) * 36 + fr]      = v0;
            sbuf[(q4 * 4 + j) * 36 + fr + 16] = v1;
        }
        // ---- readback row-contiguous + wide store (1KB per instruction) ----
        const int rr = lane >> 3, cc = (lane & 7) * 4;
        #pragma unroll
        for (int hf = 0; hf < 2; ++hf) {
            const int rx = hf * 8 + rr;
            const f32x4 vv = *(const f32x4*)&sbuf[rx * 36 + cc];
            *(f32x4*)(out + (size_t)(brow + wr * 64 + mi * 16 + rx) * TSEQ
                      + col0 + wc * 32 + cc) = vv;
        }
    }
}

extern "C" void kernel_launch(void* const* d_in, const int* in_sizes, int n_in,
                              void* d_out, int out_size, void* d_ws, size_t ws_size,
                              hipStream_t stream)
{
    const float* x  = (const float*)d_in[0];
    const float* Wq = (const float*)d_in[1];
    const float* Wk = (const float*)d_in[2];
    const float* Ww = (const float*)d_in[3];
    const float* bw = (const float*)d_in[4];
    const float* ib = (const float*)d_in[5];
    float* out = (float*)d_out;

    unsigned short* Wc = (unsigned short*)d_ws;            // 1.5 MB
    unsigned short* Qf = Wc + (size_t)384 * HID;           // 4 MB (fragment order)
    unsigned short* Kf = Qf + (size_t)NROW * 256;          // 1 MB (fragment order)
    float*          Wo = (float*)(Kf + (size_t)NROW * 64); // 128 KB

    cvt_w<<<dim3(384), dim3(256), 0, stream>>>(Wq, Wk, Ww, Wc);
    proj_mfma<<<dim3(768), dim3(256), 0, stream>>>(x, Wc, bw, Qf, Kf, Wo);
    score_all<<<dim3(9440), dim3(64), 0, stream>>>(Qf, Kf, Wo, ib, out);
}